// Round 1
// baseline (1323.803 us; speedup 1.0000x reference)
//
#include <hip/hip_runtime.h>
#include <stdint.h>

#define TPB 128
#define LDS_STRIDE 68   // 64 floats of h + pad to 16B-aligned rows, rotates banks

// One thread = one point. Encode writes enc[16] into the thread's private LDS
// row; each dense layer keeps acc[64] in VGPRs (constant-indexed, unrolled)
// and reads activations back from the private LDS row as float4 (1 LDS read
// per 256 FMAs). Weight indices are wave-uniform -> compiler emits s_load into
// SGPRs, so the FMA inner loop is pure VALU (v_fmac_f32 v, s, v).
template <int K>
__device__ __forceinline__ void dense_layer(const float* __restrict__ W,
                                            const float* __restrict__ row,
                                            float acc[64]) {
#pragma unroll
    for (int j = 0; j < 64; ++j) acc[j] = 0.f;
    for (int k0 = 0; k0 < K; k0 += 4) {
        float4 hk = *(const float4*)(row + k0);
#pragma unroll
        for (int j = 0; j < 64; ++j) {
            acc[j] = fmaf(hk.x, W[(k0 + 0) * 64 + j], acc[j]);
            acc[j] = fmaf(hk.y, W[(k0 + 1) * 64 + j], acc[j]);
            acc[j] = fmaf(hk.z, W[(k0 + 2) * 64 + j], acc[j]);
            acc[j] = fmaf(hk.w, W[(k0 + 3) * 64 + j], acc[j]);
        }
    }
}

__global__ __launch_bounds__(TPB) void hashgrid_mlp_kernel(
    const float* __restrict__ x,
    const float* __restrict__ mesh_min,
    const float* __restrict__ mesh_max,
    const float* __restrict__ tables,
    const float* __restrict__ w_in,
    const float* __restrict__ w_hidden,
    const float* __restrict__ w_out,
    float* __restrict__ out,
    int N) {
    __shared__ float lds[TPB * LDS_STRIDE];
    float* row = lds + threadIdx.x * LDS_STRIDE;

    int gid = blockIdx.x * TPB + threadIdx.x;
    if (gid >= N) return;

    float mn0 = mesh_min[0], mn1 = mesh_min[1], mn2 = mesh_min[2];
    float mx0 = mesh_max[0], mx1 = mesh_max[1], mx2 = mesh_max[2];
    float ux = (x[3 * gid + 0] - mn0) / (mx0 - mn0);
    float uy = (x[3 * gid + 1] - mn1) / (mx1 - mn1);
    float uz = (x[3 * gid + 2] - mn2) / (mx2 - mn2);

    // ---- hashgrid encode: 8 levels x 2 features -> row[0..15] ----
#pragma unroll
    for (int l = 0; l < 8; ++l) {
        const int res = 2 << l;  // 2 * 2^l
        const float* tab = tables + (size_t)l * (262144 * 2);
        float px = ux * (float)res, py = uy * (float)res, pz = uz * (float)res;
        int cx = (int)floorf(px), cy = (int)floorf(py), cz = (int)floorf(pz);
        float wx = px - (float)cx, wy = py - (float)cy, wz = pz - (float)cz;
        int cx0 = min(max(cx, 0), res), cx1 = min(max(cx + 1, 0), res);
        int cy0 = min(max(cy, 0), res), cy1 = min(max(cy + 1, 0), res);
        int cz0 = min(max(cz, 0), res), cz1 = min(max(cz + 1, 0), res);
        float f0 = 0.f, f1 = 0.f;
#pragma unroll
        for (int c = 0; c < 8; ++c) {
            int X = (c & 1) ? cx1 : cx0;
            int Y = (c & 2) ? cy1 : cy0;
            int Z = (c & 4) ? cz1 : cz0;
            float wt = ((c & 1) ? wx : 1.f - wx) *
                       ((c & 2) ? wy : 1.f - wy) *
                       ((c & 4) ? wz : 1.f - wz);
            uint32_t idx;
            if ((res + 1) * (res + 1) * (res + 1) <= 262144) {
                // dense grid at coarse levels (res <= 32)
                idx = (uint32_t)(X + Y * (res + 1) + Z * (res + 1) * (res + 1));
            } else {
                idx = ((uint32_t)X ^ ((uint32_t)Y * 2654435761u) ^
                       ((uint32_t)Z * 805459861u)) &
                      262143u;  // TABLE_SIZE = 2^18, power of two -> mask
            }
            float2 tv = *(const float2*)(tab + 2 * (size_t)idx);
            f0 = fmaf(wt, tv.x, f0);
            f1 = fmaf(wt, tv.y, f1);
        }
        row[2 * l + 0] = f0;
        row[2 * l + 1] = f1;
    }

    // ---- MLP: 16 -> 64 -> 64 -> 64 -> 64 -> 1, relu on hidden layers ----
    float acc[64];

    dense_layer<16>(w_in, row, acc);
#pragma unroll
    for (int j = 0; j < 64; ++j) row[j] = fmaxf(acc[j], 0.f);

    dense_layer<64>(w_hidden + 0 * 4096, row, acc);
#pragma unroll
    for (int j = 0; j < 64; ++j) row[j] = fmaxf(acc[j], 0.f);

    dense_layer<64>(w_hidden + 1 * 4096, row, acc);
#pragma unroll
    for (int j = 0; j < 64; ++j) row[j] = fmaxf(acc[j], 0.f);

    dense_layer<64>(w_hidden + 2 * 4096, row, acc);

    float r = 0.f;
#pragma unroll
    for (int j = 0; j < 64; ++j) r = fmaf(fmaxf(acc[j], 0.f), w_out[j], r);
    out[gid] = r;
}

extern "C" void kernel_launch(void* const* d_in, const int* in_sizes, int n_in,
                              void* d_out, int out_size, void* d_ws,
                              size_t ws_size, hipStream_t stream) {
    const float* x        = (const float*)d_in[0];
    const float* mesh_min = (const float*)d_in[1];
    const float* mesh_max = (const float*)d_in[2];
    const float* tables   = (const float*)d_in[3];
    const float* w_in     = (const float*)d_in[4];
    const float* w_hidden = (const float*)d_in[5];
    const float* w_out    = (const float*)d_in[6];
    float* out = (float*)d_out;

    int N = out_size;  // 2,097,152
    int blocks = (N + TPB - 1) / TPB;
    hipLaunchKernelGGL(hashgrid_mlp_kernel, dim3(blocks), dim3(TPB), 0, stream,
                       x, mesh_min, mesh_max, tables, w_in, w_hidden, w_out,
                       out, N);
}

// Round 2
// 408.893 us; speedup vs baseline: 3.2375x; 3.2375x over previous
//
#include <hip/hip_runtime.h>
#include <stdint.h>

typedef _Float16 half8 __attribute__((ext_vector_type(8)));
typedef float floatx4 __attribute__((ext_vector_type(4)));

#define TPB 256
#define ROWF 72  // act row stride in f16 (64 + 8 pad; 144 B, 16B-aligned, breaks pow2 banks)

// ---------------- weight prep: fp32 -> f16, swizzled into B-fragment order ----
// Fragment layout for mfma_f32_16x16x32_f16 B-operand:
//   b[lane][j] = B[k = (lane>>4)*8 + j][n = ntile*16 + (lane&15)]
// ws layout (f16 elements):
//   [0      .. 2048) : w_in   frags, nt(4) x lane(64) x j(8)   (K padded 16->32 with zeros)
//   [2048   .. 14336): w_hidden frags, (layer*2+ks)(6) x nt(4) x lane(64) x j(8)
__global__ void prep_weights(const float* __restrict__ w_in,
                             const float* __restrict__ w_hidden,
                             _Float16* __restrict__ ws) {
    int i = blockIdx.x * 256 + threadIdx.x;
    if (i < 2048) {
        int j = i & 7, lane = (i >> 3) & 63, nt = (i >> 9) & 3;
        int k = ((lane >> 4) & 3) * 8 + j;
        int n = nt * 16 + (lane & 15);
        float v = (k < 16) ? w_in[k * 64 + n] : 0.f;
        ws[i] = (_Float16)v;
    } else if (i < 14336) {
        int t = i - 2048;
        int j = t & 7, lane = (t >> 3) & 63, nt = (t >> 9) & 3;
        int ks = (t >> 11) & 1, layer = t >> 12;
        int k = ks * 32 + ((lane >> 4) & 3) * 8 + j;
        int n = nt * 16 + (lane & 15);
        ws[i] = (_Float16)w_hidden[layer * 4096 + k * 64 + n];
    }
}

// ---------------- fused hashgrid encode + f16-MFMA MLP ----------------
__global__ __launch_bounds__(TPB, 3) void hashgrid_mlp_kernel(
    const float* __restrict__ x,
    const float* __restrict__ mesh_min,
    const float* __restrict__ mesh_max,
    const float* __restrict__ tables,
    const _Float16* __restrict__ wsw,   // swizzled weights
    const float* __restrict__ w_out,
    float* __restrict__ out,
    int N) {
    __shared__ _Float16 act[4][64][ROWF];  // per-wave activation buffer, 36864 B

    const int wave = threadIdx.x >> 6;
    const int lane = threadIdx.x & 63;
    const int l15 = lane & 15;
    const int quad = lane >> 4;
    _Float16(*Aw)[ROWF] = act[wave];

    const int p = blockIdx.x * TPB + wave * 64 + lane;

    // ---- encode: 8 levels x 2 feats, scaled by 2^13 into f16 ----
    {
        float mn0 = mesh_min[0], mn1 = mesh_min[1], mn2 = mesh_min[2];
        float mx0 = mesh_max[0], mx1 = mesh_max[1], mx2 = mesh_max[2];
        float ux = (x[3 * p + 0] - mn0) / (mx0 - mn0);
        float uy = (x[3 * p + 1] - mn1) / (mx1 - mn1);
        float uz = (x[3 * p + 2] - mn2) / (mx2 - mn2);

        _Float16 e[16];
#pragma unroll
        for (int l = 0; l < 8; ++l) {
            const int res = 2 << l;
            const float* tab = tables + (size_t)l * (262144 * 2);
            float px = ux * (float)res, py = uy * (float)res, pz = uz * (float)res;
            int cx = (int)floorf(px), cy = (int)floorf(py), cz = (int)floorf(pz);
            float wx = px - (float)cx, wy = py - (float)cy, wz = pz - (float)cz;
            int cx0 = min(max(cx, 0), res), cx1 = min(max(cx + 1, 0), res);
            int cy0 = min(max(cy, 0), res), cy1 = min(max(cy + 1, 0), res);
            int cz0 = min(max(cz, 0), res), cz1 = min(max(cz + 1, 0), res);
            float f0 = 0.f, f1 = 0.f;
#pragma unroll
            for (int c = 0; c < 8; ++c) {
                int X = (c & 1) ? cx1 : cx0;
                int Y = (c & 2) ? cy1 : cy0;
                int Z = (c & 4) ? cz1 : cz0;
                float wt = ((c & 1) ? wx : 1.f - wx) *
                           ((c & 2) ? wy : 1.f - wy) *
                           ((c & 4) ? wz : 1.f - wz);
                uint32_t idx;
                if ((res + 1) * (res + 1) * (res + 1) <= 262144) {
                    idx = (uint32_t)(X + Y * (res + 1) + Z * (res + 1) * (res + 1));
                } else {
                    idx = ((uint32_t)X ^ ((uint32_t)Y * 2654435761u) ^
                           ((uint32_t)Z * 805459861u)) & 262143u;
                }
                float2 tv = *(const float2*)(tab + 2 * (size_t)idx);
                f0 = fmaf(wt, tv.x, f0);
                f1 = fmaf(wt, tv.y, f1);
            }
            e[2 * l + 0] = (_Float16)(f0 * 8192.f);
            e[2 * l + 1] = (_Float16)(f1 * 8192.f);
        }
        half8 v0, v1, z;
#pragma unroll
        for (int j = 0; j < 8; ++j) { v0[j] = e[j]; v1[j] = e[8 + j]; z[j] = (_Float16)0.f; }
        *(half8*)&Aw[lane][0] = v0;
        *(half8*)&Aw[lane][8] = v1;
        *(half8*)&Aw[lane][16] = z;   // zero-pad K 16->32 for layer 1
        *(half8*)&Aw[lane][24] = z;
    }

    // ---- MLP via mfma_f32_16x16x32_f16 ----
    floatx4 C[4][4];  // [mtile][ntile]

    // layer 1: enc(16, padded to 32) -> 64
    {
        half8 b[4];
#pragma unroll
        for (int nt = 0; nt < 4; ++nt)
            b[nt] = *(const half8*)(wsw + nt * 512 + lane * 8);
#pragma unroll
        for (int mt = 0; mt < 4; ++mt) {
            half8 a = *(const half8*)&Aw[mt * 16 + l15][quad * 8];
#pragma unroll
            for (int nt = 0; nt < 4; ++nt) {
                floatx4 zero = {0.f, 0.f, 0.f, 0.f};
                C[mt][nt] = __builtin_amdgcn_mfma_f32_16x16x32_f16(a, b[nt], zero, 0, 0, 0);
            }
        }
        // relu + write back (C/D layout: col=lane&15, row=quad*4+reg)
#pragma unroll
        for (int mt = 0; mt < 4; ++mt)
#pragma unroll
            for (int nt = 0; nt < 4; ++nt)
#pragma unroll
                for (int r = 0; r < 4; ++r)
                    Aw[mt * 16 + quad * 4 + r][nt * 16 + l15] =
                        (_Float16)fmaxf(C[mt][nt][r], 0.f);
    }

    // layers 2..4: 64 -> 64
#pragma unroll
    for (int layer = 0; layer < 3; ++layer) {
        half8 b[2][4];  // [ks][nt]
#pragma unroll
        for (int ks = 0; ks < 2; ++ks)
#pragma unroll
            for (int nt = 0; nt < 4; ++nt)
                b[ks][nt] = *(const half8*)(wsw + 2048 + ((layer * 2 + ks) * 4 + nt) * 512 + lane * 8);
#pragma unroll
        for (int mt = 0; mt < 4; ++mt) {
            int m = mt * 16 + l15;
            half8 a0 = *(const half8*)&Aw[m][quad * 8];
            half8 a1 = *(const half8*)&Aw[m][32 + quad * 8];
#pragma unroll
            for (int nt = 0; nt < 4; ++nt) {
                floatx4 zero = {0.f, 0.f, 0.f, 0.f};
                floatx4 t = __builtin_amdgcn_mfma_f32_16x16x32_f16(a0, b[0][nt], zero, 0, 0, 0);
                C[mt][nt] = __builtin_amdgcn_mfma_f32_16x16x32_f16(a1, b[1][nt], t, 0, 0, 0);
            }
        }
#pragma unroll
        for (int mt = 0; mt < 4; ++mt)
#pragma unroll
            for (int nt = 0; nt < 4; ++nt)
#pragma unroll
                for (int r = 0; r < 4; ++r)
                    Aw[mt * 16 + quad * 4 + r][nt * 16 + l15] =
                        (_Float16)fmaxf(C[mt][nt][r], 0.f);
    }

    // output layer: h4(64) . w_out -> scalar, unscale by 2^-13
    {
        float r = 0.f;
#pragma unroll
        for (int k0 = 0; k0 < 8; ++k0) {
            half8 v = *(const half8*)&Aw[lane][k0 * 8];
#pragma unroll
            for (int j = 0; j < 8; ++j)
                r = fmaf((float)v[j], w_out[k0 * 8 + j], r);
        }
        out[p] = r * (1.f / 8192.f);
    }
}

extern "C" void kernel_launch(void* const* d_in, const int* in_sizes, int n_in,
                              void* d_out, int out_size, void* d_ws,
                              size_t ws_size, hipStream_t stream) {
    const float* x        = (const float*)d_in[0];
    const float* mesh_min = (const float*)d_in[1];
    const float* mesh_max = (const float*)d_in[2];
    const float* tables   = (const float*)d_in[3];
    const float* w_in     = (const float*)d_in[4];
    const float* w_hidden = (const float*)d_in[5];
    const float* w_out    = (const float*)d_in[6];
    float* out = (float*)d_out;
    _Float16* wsw = (_Float16*)d_ws;  // needs 28672 B

    hipLaunchKernelGGL(prep_weights, dim3(56), dim3(256), 0, stream,
                       w_in, w_hidden, wsw);

    int N = out_size;  // 2,097,152 (multiple of 256)
    hipLaunchKernelGGL(hashgrid_mlp_kernel, dim3(N / TPB), dim3(TPB), 0, stream,
                       x, mesh_min, mesh_max, tables, wsw, w_out, out, N);
}

// Round 3
// 376.912 us; speedup vs baseline: 3.5122x; 1.0849x over previous
//
#include <hip/hip_runtime.h>
#include <stdint.h>

typedef _Float16 half4 __attribute__((ext_vector_type(4)));
typedef float floatx4 __attribute__((ext_vector_type(4)));

#define TPB 256
#define ENC_ROW 20  // f16 stride per point-row in the encode->layer1 LDS handoff

// ---------------- weight prep: fp32 -> f16, A-fragment order ----------------
// mfma_f32_16x16x16f16 A-operand layout: a[lane][j] = A[i = lane&15][k = (lane>>4)*4 + j]
// We compute transposed (D = W^T * H^T), so A[i=n_out][k] = W[k][n_out].
// ws layout (f16):
//   [0    .. 1024) : w_in  frags:  mt(4) x lane(64) x j(4)          (K=16, 1 kstep)
//   [1024 ..13312) : w_hid frags:  layer(3) x kt(4) x mt(4) x lane(64) x j(4)
__global__ void prep_weights(const float* __restrict__ w_in,
                             const float* __restrict__ w_hidden,
                             _Float16* __restrict__ ws) {
    int i = blockIdx.x * 256 + threadIdx.x;
    if (i < 1024) {
        int j = i & 3, lane = (i >> 2) & 63, mt = i >> 8;
        int k = ((lane >> 4) & 3) * 4 + j;          // 0..15
        int n = mt * 16 + (lane & 15);
        ws[i] = (_Float16)w_in[k * 64 + n];
    } else if (i < 13312) {
        int t = i - 1024;
        int j = t & 3, lane = (t >> 2) & 63;
        int mt = (t >> 8) & 3, kt = (t >> 10) & 3, layer = t >> 12;
        int k = kt * 16 + ((lane >> 4) & 3) * 4 + j;
        int n = mt * 16 + (lane & 15);
        ws[i] = (_Float16)w_hidden[layer * 4096 + k * 64 + n];
    }
}

// ---------------- fused hashgrid encode + register-chained MFMA MLP ----------
__global__ __launch_bounds__(TPB, 3) void hashgrid_mlp_kernel(
    const float* __restrict__ x,
    const float* __restrict__ mesh_min,
    const float* __restrict__ mesh_max,
    const float* __restrict__ tables,
    const _Float16* __restrict__ ws,
    const float* __restrict__ w_out,
    float* __restrict__ out,
    int N) {
    __shared__ _Float16 encbuf[4][64][ENC_ROW];  // per-wave, 2.5 KB each

    const int wave = threadIdx.x >> 6;
    const int lane = threadIdx.x & 63;
    const int l15 = lane & 15;
    const int quad = lane >> 4;
    const int wavebase = blockIdx.x * TPB + wave * 64;
    const int p = wavebase + lane;

    // ---- hashgrid encode (thread -> its own point), scaled by 2^13 ----
    {
        float mn0 = mesh_min[0], mn1 = mesh_min[1], mn2 = mesh_min[2];
        float mx0 = mesh_max[0], mx1 = mesh_max[1], mx2 = mesh_max[2];
        float ux = (x[3 * p + 0] - mn0) / (mx0 - mn0);
        float uy = (x[3 * p + 1] - mn1) / (mx1 - mn1);
        float uz = (x[3 * p + 2] - mn2) / (mx2 - mn2);

        _Float16 e[16];
#pragma unroll
        for (int l = 0; l < 8; ++l) {
            const int res = 2 << l;
            const float* tab = tables + (size_t)l * (262144 * 2);
            float px = ux * (float)res, py = uy * (float)res, pz = uz * (float)res;
            int cx = (int)floorf(px), cy = (int)floorf(py), cz = (int)floorf(pz);
            float wx = px - (float)cx, wy = py - (float)cy, wz = pz - (float)cz;
            int cx0 = min(max(cx, 0), res), cx1 = min(max(cx + 1, 0), res);
            int cy0 = min(max(cy, 0), res), cy1 = min(max(cy + 1, 0), res);
            int cz0 = min(max(cz, 0), res), cz1 = min(max(cz + 1, 0), res);
            float f0 = 0.f, f1 = 0.f;
#pragma unroll
            for (int c = 0; c < 8; ++c) {
                int X = (c & 1) ? cx1 : cx0;
                int Y = (c & 2) ? cy1 : cy0;
                int Z = (c & 4) ? cz1 : cz0;
                float wt = ((c & 1) ? wx : 1.f - wx) *
                           ((c & 2) ? wy : 1.f - wy) *
                           ((c & 4) ? wz : 1.f - wz);
                uint32_t idx;
                if ((res + 1) * (res + 1) * (res + 1) <= 262144) {
                    idx = (uint32_t)(X + Y * (res + 1) + Z * (res + 1) * (res + 1));
                } else {
                    idx = ((uint32_t)X ^ ((uint32_t)Y * 2654435761u) ^
                           ((uint32_t)Z * 805459861u)) & 262143u;
                }
                float2 tv = *(const float2*)(tab + 2 * (size_t)idx);
                f0 = fmaf(wt, tv.x, f0);
                f1 = fmaf(wt, tv.y, f1);
            }
            e[2 * l + 0] = (_Float16)(f0 * 8192.f);
            e[2 * l + 1] = (_Float16)(f1 * 8192.f);
        }
#pragma unroll
        for (int v = 0; v < 4; ++v) {
            half4 t;
#pragma unroll
            for (int j = 0; j < 4; ++j) t[j] = e[v * 4 + j];
            *(half4*)&encbuf[wave][lane][v * 4] = t;
        }
    }
    __syncthreads();

    // ---- layer 1: enc(16) -> 64, transposed: D = Win^T * Enc^T ----
    floatx4 C[4][4];  // [mt = out-feature tile][nt = point tile]
    {
        half4 b[4];
#pragma unroll
        for (int nt = 0; nt < 4; ++nt)
            b[nt] = *(const half4*)&encbuf[wave][nt * 16 + l15][quad * 4];
#pragma unroll
        for (int mt = 0; mt < 4; ++mt) {
            half4 a = *(const half4*)(ws + mt * 256 + lane * 4);
#pragma unroll
            for (int nt = 0; nt < 4; ++nt) {
                floatx4 zero = {0.f, 0.f, 0.f, 0.f};
                C[mt][nt] = __builtin_amdgcn_mfma_f32_16x16x16f16(a, b[nt], zero, 0, 0, 0);
            }
        }
    }

    // ---- layers 2..4: 64 -> 64; C regs (relu+cvt) ARE the next B-frags ----
#pragma unroll
    for (int layer = 0; layer < 3; ++layer) {
        half4 b[4][4];  // [kt][nt]
#pragma unroll
        for (int kt = 0; kt < 4; ++kt)
#pragma unroll
            for (int nt = 0; nt < 4; ++nt)
#pragma unroll
                for (int j = 0; j < 4; ++j)
                    b[kt][nt][j] = (_Float16)fmaxf(C[kt][nt][j], 0.f);
#pragma unroll
        for (int mt = 0; mt < 4; ++mt) {
            half4 a[4];
#pragma unroll
            for (int kt = 0; kt < 4; ++kt)
                a[kt] = *(const half4*)(ws + 1024 + ((layer * 4 + kt) * 4 + mt) * 256 + lane * 4);
#pragma unroll
            for (int nt = 0; nt < 4; ++nt) {
                floatx4 acc = {0.f, 0.f, 0.f, 0.f};
#pragma unroll
                for (int kt = 0; kt < 4; ++kt)
                    acc = __builtin_amdgcn_mfma_f32_16x16x16f16(a[kt], b[kt][nt], acc, 0, 0, 0);
                C[mt][nt] = acc;
            }
        }
    }

    // ---- output layer: relu(h4) . w_out, reduce across quads, unscale ----
    {
        float s[4] = {0.f, 0.f, 0.f, 0.f};
#pragma unroll
        for (int mt = 0; mt < 4; ++mt) {
            float4 wo = *(const float4*)(w_out + mt * 16 + quad * 4);
#pragma unroll
            for (int nt = 0; nt < 4; ++nt) {
                s[nt] = fmaf(fmaxf(C[mt][nt][0], 0.f), wo.x, s[nt]);
                s[nt] = fmaf(fmaxf(C[mt][nt][1], 0.f), wo.y, s[nt]);
                s[nt] = fmaf(fmaxf(C[mt][nt][2], 0.f), wo.z, s[nt]);
                s[nt] = fmaf(fmaxf(C[mt][nt][3], 0.f), wo.w, s[nt]);
            }
        }
#pragma unroll
        for (int nt = 0; nt < 4; ++nt) {
            s[nt] += __shfl_xor(s[nt], 16, 64);
            s[nt] += __shfl_xor(s[nt], 32, 64);
        }
        float r = (quad & 1) ? ((quad & 2) ? s[3] : s[1])
                             : ((quad & 2) ? s[2] : s[0]);
        out[wavebase + quad * 16 + l15] = r * (1.f / 8192.f);
    }
}

extern "C" void kernel_launch(void* const* d_in, const int* in_sizes, int n_in,
                              void* d_out, int out_size, void* d_ws,
                              size_t ws_size, hipStream_t stream) {
    const float* x        = (const float*)d_in[0];
    const float* mesh_min = (const float*)d_in[1];
    const float* mesh_max = (const float*)d_in[2];
    const float* tables   = (const float*)d_in[3];
    const float* w_in     = (const float*)d_in[4];
    const float* w_hidden = (const float*)d_in[5];
    const float* w_out    = (const float*)d_in[6];
    float* out = (float*)d_out;
    _Float16* ws = (_Float16*)d_ws;  // 26624 B used

    hipLaunchKernelGGL(prep_weights, dim3(52), dim3(256), 0, stream,
                       w_in, w_hidden, ws);

    int N = out_size;  // 2,097,152 (multiple of 256)
    hipLaunchKernelGGL(hashgrid_mlp_kernel, dim3(N / TPB), dim3(TPB), 0, stream,
                       x, mesh_min, mesh_max, tables, ws, w_out, out, N);
}